// Round 5
// baseline (715.999 us; speedup 1.0000x reference)
//
#include <hip/hip_runtime.h>
#include <cstddef>
#include <cstdint>

#define N_NODES 20000
#define N_EDGES 320000

typedef __attribute__((ext_vector_type(8))) short bf8_t;   // 8 x bf16
typedef __attribute__((ext_vector_type(4))) float f4_t;    // MFMA acc / float4
typedef __attribute__((ext_vector_type(4))) short s4_t;    // 4 x bf16 (8 B)

__device__ __forceinline__ short f2bf(float f) {
  unsigned u = __float_as_uint(f);
  u += 0x7fff + ((u >> 16) & 1);   // round-to-nearest-even
  return (short)(u >> 16);
}

// ======================= CSR build =======================
__global__ void count_deg_kernel(const int* __restrict__ dst, int* __restrict__ deg, int e_cnt) {
  int e = blockIdx.x * blockDim.x + threadIdx.x;
  if (e < e_cnt) atomicAdd(&deg[dst[e]], 1);
}

__global__ void scan_kernel(const int* __restrict__ deg, int* __restrict__ rowptr,
                            int* __restrict__ cursor, int n) {
  __shared__ int sdata[1024];
  __shared__ int s_carry;
  int tid = threadIdx.x;
  if (tid == 0) s_carry = 0;
  __syncthreads();
  for (int base = 0; base < n; base += 1024) {
    int idx = base + tid;
    int v = (idx < n) ? deg[idx] : 0;
    sdata[tid] = v;
    __syncthreads();
    for (int off = 1; off < 1024; off <<= 1) {
      int t = (tid >= off) ? sdata[tid - off] : 0;
      __syncthreads();
      sdata[tid] += t;
      __syncthreads();
    }
    int excl = sdata[tid] - v;
    if (idx < n) { int val = s_carry + excl; rowptr[idx] = val; cursor[idx] = val; }
    __syncthreads();
    if (tid == 0) s_carry += sdata[1023];
    __syncthreads();
  }
  if (tid == 0) rowptr[n] = s_carry;
}

__global__ void fill_csr_kernel(const int* __restrict__ src, const int* __restrict__ dst,
                                int* __restrict__ cursor, int* __restrict__ csr_src, int e_cnt) {
  int e = blockIdx.x * blockDim.x + threadIdx.x;
  if (e < e_cnt) {
    int pos = atomicAdd(&cursor[dst[e]], 1);
    csr_src[pos] = src[e];
  }
}

// ======================= weight prep: fp32 -> bf16 transposed =======================
__global__ void prep_weights_kernel(const float* __restrict__ w1, const float* __restrict__ w2,
                                    short* __restrict__ w1t, short* __restrict__ w2t) {
  int i = blockIdx.x * blockDim.x + threadIdx.x;
  if (i < 16384) {
    int n = i >> 6, k = i & 63;
    w1t[n * 64 + k] = f2bf(w1[k * 256 + n]);
  } else if (i < 32768) {
    int j = i - 16384;
    int n = j >> 8, k = j & 255;
    w2t[n * 256 + k] = f2bf(w2[k * 64 + n]);
  }
}

// ======================= fp32 GEMM bodies =======================
template<int KIN>
__device__ __forceinline__ void gemm_body(
    const float* __restrict__ A, const float* __restrict__ W, int wld, int cb,
    int block_m, int M, float (&acc)[8][4],
    float (*As)[128 + 4], float (*Ws)[64 + 4])
{
  int tid = threadIdx.x;
  int tx = tid & 15;
  int ty = tid >> 4;
  #pragma unroll
  for (int i = 0; i < 8; ++i)
    #pragma unroll
    for (int j = 0; j < 4; ++j) acc[i][j] = 0.f;

  for (int k0 = 0; k0 < KIN; k0 += 16) {
    #pragma unroll
    for (int rep = 0; rep < 2; ++rep) {
      int ar = (tid >> 2) + rep * 64;
      int ak = (tid & 3) * 4;
      int gr = block_m + ar;
      float4 v = make_float4(0.f, 0.f, 0.f, 0.f);
      if (gr < M) v = *(const float4*)&A[(size_t)gr * KIN + k0 + ak];
      As[ak + 0][ar] = v.x; As[ak + 1][ar] = v.y;
      As[ak + 2][ar] = v.z; As[ak + 3][ar] = v.w;
    }
    {
      int wr = tid >> 4;
      int wc = (tid & 15) * 4;
      float4 v = *(const float4*)&W[(size_t)(k0 + wr) * wld + cb + wc];
      Ws[wr][wc + 0] = v.x; Ws[wr][wc + 1] = v.y;
      Ws[wr][wc + 2] = v.z; Ws[wr][wc + 3] = v.w;
    }
    __syncthreads();
    #pragma unroll
    for (int k = 0; k < 16; ++k) {
      float a[8], w[4];
      #pragma unroll
      for (int i = 0; i < 8; ++i) a[i] = As[k][ty * 8 + i];
      #pragma unroll
      for (int j = 0; j < 4; ++j) w[j] = Ws[k][tx * 4 + j];
      #pragma unroll
      for (int i = 0; i < 8; ++i)
        #pragma unroll
        for (int j = 0; j < 4; ++j) acc[i][j] = fmaf(a[i], w[j], acc[i][j]);
    }
    __syncthreads();
  }
}

// MODE 0: raw.  MODE 3: relu(v + bias).
template<int KIN, int MODE>
__global__ __launch_bounds__(256) void gemm64_kernel(
    const float* __restrict__ A, const float* __restrict__ W, int wld,
    const float* __restrict__ bias, float* __restrict__ out, int old, int M)
{
  __shared__ float As[16][128 + 4];
  __shared__ float Ws[16][64 + 4];
  float acc[8][4];
  int block_m = (int)blockIdx.x * 128;
  int cb = (int)blockIdx.y * 64;
  gemm_body<KIN>(A, W, wld, cb, block_m, M, acc, As, Ws);

  int tid = threadIdx.x;
  int tx = tid & 15, ty = tid >> 4;
  int gc = cb + tx * 4;
  #pragma unroll
  for (int i = 0; i < 8; ++i) {
    int gr = block_m + ty * 8 + i;
    if (gr >= M) continue;
    size_t idx = (size_t)gr * old + gc;
    float t0 = acc[i][0], t1 = acc[i][1], t2 = acc[i][2], t3 = acc[i][3];
    if (MODE == 3) {
      t0 = fmaxf(t0 + bias[gc + 0], 0.f);
      t1 = fmaxf(t1 + bias[gc + 1], 0.f);
      t2 = fmaxf(t2 + bias[gc + 2], 0.f);
      t3 = fmaxf(t3 + bias[gc + 3], 0.f);
    }
    *(float4*)&out[idx] = make_float4(t0, t1, t2, t3);
  }
}

// Pair GEMM for 256-wide projections: y<4 -> A@Wl colblock y -> xl; y>=4 -> A@Wr -> xr.
template<int KIN>
__global__ __launch_bounds__(256) void gemm_pair256_kernel(
    const float* __restrict__ A,
    const float* __restrict__ Wl, const float* __restrict__ Wr,
    float* __restrict__ xl, float* __restrict__ xr, int M)
{
  __shared__ float As[16][128 + 4];
  __shared__ float Ws[16][64 + 4];
  float acc[8][4];
  int block_m = (int)blockIdx.x * 128;
  int y = (int)blockIdx.y;
  const float* W = (y < 4) ? Wl : Wr;
  float* out = (y < 4) ? xl : xr;
  int cb = (y & 3) * 64;
  gemm_body<KIN>(A, W, 256, cb, block_m, M, acc, As, Ws);

  int tid = threadIdx.x;
  int tx = tid & 15, ty = tid >> 4;
  int gc = cb + tx * 4;
  #pragma unroll
  for (int i = 0; i < 8; ++i) {
    int gr = block_m + ty * 8 + i;
    if (gr >= M) continue;
    *(float4*)&out[(size_t)gr * 256 + gc] =
        make_float4(acc[i][0], acc[i][1], acc[i][2], acc[i][3]);
  }
}

// Dual 64-col GEMM: y==0 -> A@W0 -> out0 ; ==1 -> A@W1 -> out1.
template<int KIN>
__global__ __launch_bounds__(256) void gemm64_dual_kernel(
    const float* __restrict__ A,
    const float* __restrict__ W0, const float* __restrict__ W1, int wld,
    float* __restrict__ out0, float* __restrict__ out1, int M)
{
  __shared__ float As[16][128 + 4];
  __shared__ float Ws[16][64 + 4];
  float acc[8][4];
  int block_m = (int)blockIdx.x * 128;
  const float* W = (blockIdx.y == 0) ? W0 : W1;
  float* out = (blockIdx.y == 0) ? out0 : out1;
  gemm_body<KIN>(A, W, wld, 0, block_m, M, acc, As, Ws);

  int tid = threadIdx.x;
  int tx = tid & 15, ty = tid >> 4;
  int gc = tx * 4;
  #pragma unroll
  for (int i = 0; i < 8; ++i) {
    int gr = block_m + ty * 8 + i;
    if (gr >= M) continue;
    *(float4*)&out[(size_t)gr * 64 + gc] =
        make_float4(acc[i][0], acc[i][1], acc[i][2], acc[i][3]);
  }
}

// ======================= GATv2 aggregation =======================
#define AGG_UPD(P, X)                                     \
  {                                                       \
    float mn = fmaxf(m, (P));                             \
    float sc = __expf(m - mn);                            \
    float w  = __expf((P) - mn);                          \
    z = z * sc + w;                                       \
    acc = acc * sc + w * (X);                             \
    m = mn;                                               \
  }

#define AGG_BODY(STR)                                                         \
  float m, z, acc;                                                            \
  {                                                                           \
    float xs = xl[(size_t)d * STR + tid];                                     \
    float t = xs + xr_v;                                                      \
    t = t > 0.f ? t : 0.2f * t;                                               \
    float p = t * att_v;                                                      \
    _Pragma("unroll")                                                         \
    for (int off = 32; off > 0; off >>= 1) p += __shfl_xor(p, off, 64);       \
    m = p; z = 1.f; acc = xs;                                                 \
  }                                                                           \
  int j = 0;                                                                  \
  for (; j + 8 <= deg; j += 8) {                                              \
    int s[8]; float xv[8], p[8];                                              \
    _Pragma("unroll")                                                         \
    for (int u = 0; u < 8; ++u) s[u] = csr_src[row0 + j + u];                 \
    _Pragma("unroll")                                                         \
    for (int u = 0; u < 8; ++u) xv[u] = xl[(size_t)s[u] * STR + tid];         \
    _Pragma("unroll")                                                         \
    for (int u = 0; u < 8; ++u) {                                             \
      float t = xv[u] + xr_v;                                                 \
      t = t > 0.f ? t : 0.2f * t;                                             \
      p[u] = t * att_v;                                                       \
    }                                                                         \
    _Pragma("unroll")                                                         \
    for (int off = 32; off > 0; off >>= 1) {                                  \
      _Pragma("unroll")                                                       \
      for (int u = 0; u < 8; ++u) p[u] += __shfl_xor(p[u], off, 64);          \
    }                                                                         \
    _Pragma("unroll")                                                         \
    for (int u = 0; u < 8; ++u) AGG_UPD(p[u], xv[u]);                         \
  }                                                                           \
  for (; j + 4 <= deg; j += 4) {                                              \
    int s[4]; float xv[4], p[4];                                              \
    _Pragma("unroll")                                                         \
    for (int u = 0; u < 4; ++u) s[u] = csr_src[row0 + j + u];                 \
    _Pragma("unroll")                                                         \
    for (int u = 0; u < 4; ++u) xv[u] = xl[(size_t)s[u] * STR + tid];         \
    _Pragma("unroll")                                                         \
    for (int u = 0; u < 4; ++u) {                                             \
      float t = xv[u] + xr_v;                                                 \
      t = t > 0.f ? t : 0.2f * t;                                             \
      p[u] = t * att_v;                                                       \
    }                                                                         \
    _Pragma("unroll")                                                         \
    for (int off = 32; off > 0; off >>= 1) {                                  \
      _Pragma("unroll")                                                       \
      for (int u = 0; u < 4; ++u) p[u] += __shfl_xor(p[u], off, 64);          \
    }                                                                         \
    _Pragma("unroll")                                                         \
    for (int u = 0; u < 4; ++u) AGG_UPD(p[u], xv[u]);                         \
  }                                                                           \
  for (; j < deg; ++j) {                                                      \
    int s = csr_src[row0 + j];                                                \
    float x = xl[(size_t)s * STR + tid];                                      \
    float t = x + xr_v;                                                       \
    t = t > 0.f ? t : 0.2f * t;                                               \
    float p = t * att_v;                                                      \
    _Pragma("unroll")                                                         \
    for (int off = 32; off > 0; off >>= 1) p += __shfl_xor(p, off, 64);       \
    AGG_UPD(p, x);                                                            \
  }

// single-head, one wave per destination, stride 64
template<bool ELU>
__global__ __launch_bounds__(64) void gat_agg64(
    const float* __restrict__ xl, const float* __restrict__ xr,
    const float* __restrict__ att, const float* __restrict__ bias,
    const int* __restrict__ rowptr, const int* __restrict__ csr_src,
    float* __restrict__ out, int old)
{
  int d = blockIdx.x;
  int tid = threadIdx.x;
  int row0 = rowptr[d];
  int deg = rowptr[d + 1] - row0;
  float xr_v = xr[(size_t)d * 64 + tid];
  float att_v = att[tid];
  AGG_BODY(64)
  float val = acc / z + bias[tid];
  if (ELU) val = val > 0.f ? val : __expf(val) - 1.f;
  out[(size_t)d * old + tid] = val;
}

// 4-head fused: block=256 (wave h = head h), xl/xr/out stride 256, concat layout.
template<bool ELU>
__global__ __launch_bounds__(256) void gat_agg256(
    const float* __restrict__ xl, const float* __restrict__ xr,
    const float* __restrict__ att, const float* __restrict__ bias,
    const int* __restrict__ rowptr, const int* __restrict__ csr_src,
    float* __restrict__ out)
{
  int d = blockIdx.x;
  int tid = threadIdx.x;
  int row0 = rowptr[d];
  int deg = rowptr[d + 1] - row0;
  float xr_v = xr[(size_t)d * 256 + tid];
  float att_v = att[tid];
  AGG_BODY(256)
  float val = acc / z + bias[tid];
  if (ELU) val = val > 0.f ? val : __expf(val) - 1.f;
  out[(size_t)d * 256 + tid] = val;
}

// ======================= fused MFMA chunk kernel (edge rows >= N) =======================
// Per 128-row block, 4 waves x 32 rows each, wave-private LDS, NO barriers.
// GEMM1 computed TRANSPOSED (A-op = W1^T frags, B-op = row frags) so the
// C-layout hands each lane 4 consecutive G-columns of one row -> ds_write_b64;
// readback for GEMM2 A-frags is ds_read_b128. Both 2-way-aliased max (free).
__global__ __launch_bounds__(256) void chunk_fused_kernel(
    const float* __restrict__ A,      // edge_type + N*64
    const short* __restrict__ W1t,    // [256][64] bf16 (n,k)  == W1^T
    const short* __restrict__ W2t,    // [64][256] bf16 (n,k)  == W2^T
    const float* __restrict__ b1,     // [256]
    const float* __restrict__ b2,     // [64]
    const float* __restrict__ wp,     // [64][2]
    const int* __restrict__ dstN,     // dst + N_NODES
    float* __restrict__ msg, int Mtot)
{
  __shared__ short gbuf[4][32][72];   // per-wave [row][col], pad 64->72 (144 B rows)
  int tid = threadIdx.x;
  int w = tid >> 6;
  int lane = tid & 63;
  int quad = lane >> 4;
  int l15 = lane & 15;
  int row_base = (int)blockIdx.x * 128 + w * 32;

  // row frags: lane l15 = row, k = ks*32 + quad*8 + j  (A-op for GEMM2 / B-op for GEMM1)
  bf8_t a1[2][2];
  #pragma unroll
  for (int rt = 0; rt < 2; ++rt) {
    int r = row_base + rt * 16 + l15;
    int rc = r < Mtot ? r : Mtot - 1;
    const float* ap = A + (size_t)rc * 64 + quad * 8;
    #pragma unroll
    for (int ks = 0; ks < 2; ++ks) {
      float4 v0 = *(const float4*)(ap + ks * 32);
      float4 v1 = *(const float4*)(ap + ks * 32 + 4);
      bf8_t f;
      f[0] = f2bf(v0.x); f[1] = f2bf(v0.y); f[2] = f2bf(v0.z); f[3] = f2bf(v0.w);
      f[4] = f2bf(v1.x); f[5] = f2bf(v1.y); f[6] = f2bf(v1.z); f[7] = f2bf(v1.w);
      a1[rt][ks] = f;
    }
  }

  f4_t accr[2][4];
  #pragma unroll
  for (int rt = 0; rt < 2; ++rt)
    #pragma unroll
    for (int nt = 0; nt < 4; ++nt) {
      f4_t zz = {0.f, 0.f, 0.f, 0.f};
      accr[rt][nt] = zz;
    }

  for (int cc = 0; cc < 4; ++cc) {
    // ---- GEMM1 transposed: D = W1^T-frag (A-op) x row-frag (B-op) = G^T tile ----
    f4_t accg[2][4];
    #pragma unroll
    for (int rt = 0; rt < 2; ++rt)
      #pragma unroll
      for (int nt = 0; nt < 4; ++nt) {
        f4_t zz = {0.f, 0.f, 0.f, 0.f};
        accg[rt][nt] = zz;
      }
    #pragma unroll
    for (int nt = 0; nt < 4; ++nt) {
      const short* wb = W1t + (cc * 64 + nt * 16 + l15) * 64 + quad * 8;
      bf8_t w0 = *(const bf8_t*)(wb);
      bf8_t w1 = *(const bf8_t*)(wb + 32);
      #pragma unroll
      for (int rt = 0; rt < 2; ++rt) {
        accg[rt][nt] = __builtin_amdgcn_mfma_f32_16x16x32_bf16(w0, a1[rt][0], accg[rt][nt], 0, 0, 0);
        accg[rt][nt] = __builtin_amdgcn_mfma_f32_16x16x32_bf16(w1, a1[rt][1], accg[rt][nt], 0, 0, 0);
      }
    }
    // ---- epilogue: lane reg r = G[row=rt*16+l15][col=nt*16+quad*4+r] ----
    #pragma unroll
    for (int nt = 0; nt < 4; ++nt) {
      f4_t b4 = *(const f4_t*)&b1[cc * 64 + nt * 16 + quad * 4];
      #pragma unroll
      for (int rt = 0; rt < 2; ++rt) {
        s4_t pk;
        #pragma unroll
        for (int r = 0; r < 4; ++r) {
          float v = accg[rt][nt][r] + b4[r];
          v = v > 0.f ? v : __expf(v) - 1.f;
          pk[r] = f2bf(v);
        }
        *(s4_t*)&gbuf[w][rt * 16 + l15][nt * 16 + quad * 4] = pk;
      }
    }
    // ---- read back as A-frags (in-order DS per wave: no barrier needed) ----
    bf8_t a2[2][2];
    #pragma unroll
    for (int rt = 0; rt < 2; ++rt)
      #pragma unroll
      for (int ks = 0; ks < 2; ++ks)
        a2[rt][ks] = *(const bf8_t*)&gbuf[w][rt * 16 + l15][ks * 32 + quad * 8];
    // ---- GEMM2 accumulate over this K-chunk ----
    #pragma unroll
    for (int nt = 0; nt < 4; ++nt) {
      const short* wb = W2t + (nt * 16 + l15) * 256 + cc * 64 + quad * 8;
      bf8_t bk0 = *(const bf8_t*)(wb);
      bf8_t bk1 = *(const bf8_t*)(wb + 32);
      #pragma unroll
      for (int rt = 0; rt < 2; ++rt) {
        accr[rt][nt] = __builtin_amdgcn_mfma_f32_16x16x32_bf16(a2[rt][0], bk0, accr[rt][nt], 0, 0, 0);
        accr[rt][nt] = __builtin_amdgcn_mfma_f32_16x16x32_bf16(a2[rt][1], bk1, accr[rt][nt], 0, 0, 0);
      }
    }
  }

  // ---- R epilogue: +b2, dot with wp, reduce over l15, atomicAdd ----
  #pragma unroll
  for (int rt = 0; rt < 2; ++rt) {
    float p0[4] = {0.f, 0.f, 0.f, 0.f};
    float p1[4] = {0.f, 0.f, 0.f, 0.f};
    #pragma unroll
    for (int nt = 0; nt < 4; ++nt) {
      int col = nt * 16 + l15;
      float bias = b2[col];
      float w0 = wp[col * 2 + 0], w1 = wp[col * 2 + 1];
      #pragma unroll
      for (int r = 0; r < 4; ++r) {
        float v = accr[rt][nt][r] + bias;
        p0[r] = fmaf(v, w0, p0[r]);
        p1[r] = fmaf(v, w1, p1[r]);
      }
    }
    #pragma unroll
    for (int r = 0; r < 4; ++r) {
      #pragma unroll
      for (int off = 1; off < 16; off <<= 1) {
        p0[r] += __shfl_xor(p0[r], off, 64);
        p1[r] += __shfl_xor(p1[r], off, 64);
      }
    }
    if (l15 == 0) {
      #pragma unroll
      for (int r = 0; r < 4; ++r) {
        int row = row_base + rt * 16 + quad * 4 + r;
        if (row < Mtot) {
          int d = dstN[row];
          atomicAdd(&msg[2 * d + 0], p0[r]);
          atomicAdd(&msg[2 * d + 1], p1[r]);
        }
      }
    }
  }
}

// ======================= CRF message for edge ids < N =======================
__global__ void msg_low_kernel(const float* __restrict__ edge_repr, const float* __restrict__ wp,
                               const int* __restrict__ dst, float* __restrict__ msg, int e_cnt) {
  __shared__ float swp[128];
  if (threadIdx.x < 128) swp[threadIdx.x] = wp[threadIdx.x];
  __syncthreads();
  int e = blockIdx.x * blockDim.x + threadIdx.x;
  if (e >= e_cnt) return;
  const float* er = edge_repr + (size_t)e * 64;
  float a0 = 0.f, a1 = 0.f;
  #pragma unroll
  for (int k = 0; k < 64; ++k) {
    float v = er[k];
    a0 = fmaf(v, swp[2 * k + 0], a0);
    a1 = fmaf(v, swp[2 * k + 1], a1);
  }
  int d = dst[e];
  atomicAdd(&msg[2 * d + 0], a0);
  atomicAdd(&msg[2 * d + 1], a1);
}

// ======================= Heads =======================
__global__ void head_kernel(const float* __restrict__ node_repr, const float* __restrict__ ph,
                            const float* __restrict__ msg, const float* __restrict__ wu,
                            const float* __restrict__ bu, const float* __restrict__ w2,
                            const float* __restrict__ b2, float* __restrict__ out, int n) {
  __shared__ float swu[128];
  __shared__ float sw2[256];
  int tid = threadIdx.x;
  if (tid < 128) swu[tid] = wu[tid];
  sw2[tid] = w2[tid];
  __syncthreads();
  int i = blockIdx.x * blockDim.x + tid;
  if (i >= n) return;
  const float* nr = node_repr + (size_t)i * 64;
  float u0 = bu[0], u1 = bu[1];
  #pragma unroll
  for (int k = 0; k < 64; ++k) {
    float v = nr[k];
    u0 = fmaf(v, swu[2 * k + 0], u0);
    u1 = fmaf(v, swu[2 * k + 1], u1);
  }
  float v0 = u0 + msg[2 * i + 0];
  float v1 = u1 + msg[2 * i + 1];
  float mx = fmaxf(v0, v1);
  float lse = mx + logf(__expf(v0 - mx) + __expf(v1 - mx));
  out[2 * i + 0] = v0 - lse;
  out[2 * i + 1] = v1 - lse;
  const float* p = ph + (size_t)i * 128;
  float p0 = b2[0], p1 = b2[1];
  #pragma unroll
  for (int k = 0; k < 128; ++k) {
    float v = p[k];
    p0 = fmaf(v, sw2[2 * k + 0], p0);
    p1 = fmaf(v, sw2[2 * k + 1], p1);
  }
  out[2 * n + 2 * i + 0] = p0;
  out[2 * n + 2 * i + 1] = p1;
}

// ======================= launch =======================
extern "C" void kernel_launch(void* const* d_in, const int* in_sizes, int n_in,
                              void* d_out, int out_size, void* d_ws, size_t ws_size,
                              hipStream_t stream) {
  const int N = N_NODES, E = N_EDGES;
  const float* x         = (const float*)d_in[0];
  const float* edge_type = (const float*)d_in[1];
  const int*   ei        = (const int*)d_in[2];
  const float* n1_wl  = (const float*)d_in[3];
  const float* n1_wr  = (const float*)d_in[4];
  const float* n1_att = (const float*)d_in[5];
  const float* n1_b   = (const float*)d_in[6];
  const float* n2_wl  = (const float*)d_in[7];
  const float* n2_wr  = (const float*)d_in[8];
  const float* n2_att = (const float*)d_in[9];
  const float* n2_b   = (const float*)d_in[10];
  const float* e1_wl  = (const float*)d_in[11];
  const float* e1_wr  = (const float*)d_in[12];
  const float* e1_att = (const float*)d_in[13];
  const float* e1_b   = (const float*)d_in[14];
  const float* e2_wl  = (const float*)d_in[15];
  const float* e2_wr  = (const float*)d_in[16];
  const float* e2_att = (const float*)d_in[17];
  const float* e2_b   = (const float*)d_in[18];
  const float* crf_wu = (const float*)d_in[19];
  const float* crf_bu = (const float*)d_in[20];
  const float* crf_wp = (const float*)d_in[21];
  const float* px_w1  = (const float*)d_in[22];
  const float* px_b1  = (const float*)d_in[23];
  const float* px_w2  = (const float*)d_in[24];
  const float* px_b2  = (const float*)d_in[25];
  float* out = (float*)d_out;
  const int* src = ei;
  const int* dst = ei + E;
  (void)in_sizes; (void)n_in; (void)out_size; (void)ws_size;

  // ---- workspace layout (~75 MB of ~327 MB) ----
  char* ws = (char*)d_ws;
  size_t off = 0;
  auto alloc = [&](size_t bytes) -> void* {
    void* p = ws + off;
    off += (bytes + 255) & ~(size_t)255;
    return p;
  };
  float* arena0 = (float*)alloc((size_t)N * 256 * 4);  // xl / [N,64] views / ph
  float* arena1 = (float*)alloc((size_t)N * 256 * 4);  // xr
  float* arena2 = (float*)alloc((size_t)N * 256 * 4);  // h / g_low
  float* ph     = arena0;
  float* B3    = (float*)alloc((size_t)N * 64 * 4);    // node_repr
  float* erlow = (float*)alloc((size_t)N * 64 * 4);    // edge_repr rows < N
  float* msg   = (float*)alloc((size_t)N * 2 * 4);
  int* deg     = (int*)alloc((size_t)N * 4);
  int* rowptr  = (int*)alloc((size_t)(N + 1) * 4);
  int* cursor  = (int*)alloc((size_t)N * 4);
  int* csr_src = (int*)alloc((size_t)E * 4);
  short* W1t   = (short*)alloc((size_t)256 * 64 * 2);
  short* W2t   = (short*)alloc((size_t)64 * 256 * 2);

  const int EB = (E + 255) / 256;
  const int NB = (N + 127) / 128;        // 157
  const int Mhigh = E - N;               // 300000
  const int CFB = (Mhigh + 127) / 128;   // 2344

  hipMemsetAsync(deg, 0, (size_t)N * 4, stream);
  hipMemsetAsync(msg, 0, (size_t)N * 2 * 4, stream);
  count_deg_kernel<<<EB, 256, 0, stream>>>(dst, deg, E);
  scan_kernel<<<1, 1024, 0, stream>>>(deg, rowptr, cursor, N);
  fill_csr_kernel<<<EB, 256, 0, stream>>>(src, dst, cursor, csr_src, E);
  prep_weights_kernel<<<128, 256, 0, stream>>>(e1_wl, e2_wl, W1t, W2t);

  // ---- node layer 1: GATv2(64 -> 4x64, concat) + elu ----
  gemm_pair256_kernel<64><<<dim3(NB, 8), 256, 0, stream>>>(x, n1_wl, n1_wr, arena0, arena1, N);
  gat_agg256<true><<<N, 256, 0, stream>>>(arena0, arena1, n1_att, n1_b, rowptr, csr_src, arena2);

  // ---- node layer 2: GATv2(256 -> 64) -> B3 ----
  gemm64_dual_kernel<256><<<dim3(NB, 2), 256, 0, stream>>>(arena2, n2_wl, n2_wr, 64, arena0, arena1, N);
  gat_agg64<false><<<N, 64, 0, stream>>>(arena0, arena1, n2_att, n2_b, rowptr, csr_src, B3, 64);

  // ---- edge layer 1, rows < N ----
  gemm_pair256_kernel<64><<<dim3(NB, 8), 256, 0, stream>>>(edge_type, e1_wl, e1_wr, arena0, arena1, N);
  gat_agg256<true><<<N, 256, 0, stream>>>(arena0, arena1, e1_att, e1_b, rowptr, csr_src, arena2);

  // ---- edge layer 2, rows < N -> erlow ----
  gemm64_dual_kernel<256><<<dim3(NB, 2), 256, 0, stream>>>(arena2, e2_wl, e2_wr, 64, arena0, arena1, N);
  gat_agg64<false><<<N, 64, 0, stream>>>(arena0, arena1, e2_att, e2_b, rowptr, csr_src, erlow, 64);

  // ---- CRF messages ----
  msg_low_kernel<<<(N + 255) / 256, 256, 0, stream>>>(erlow, crf_wp, dst, msg, N);
  chunk_fused_kernel<<<CFB, 256, 0, stream>>>(edge_type + (size_t)N * 64, W1t, W2t,
                                              e1_b, e2_b, crf_wp, dst + N, msg, Mhigh);

  // ---- heads ----
  gemm64_kernel<64, 3><<<dim3(NB, 2), 256, 0, stream>>>(B3, px_w1, 128, px_b1, ph, 128, N);
  head_kernel<<<(N + 255) / 256, 256, 0, stream>>>(B3, ph, msg, crf_wu, crf_bu, px_w2, px_b2, out, N);
}

// Round 6
// 691.687 us; speedup vs baseline: 1.0351x; 1.0351x over previous
//
#include <hip/hip_runtime.h>
#include <cstddef>
#include <cstdint>

#define N_NODES 20000
#define N_EDGES 320000

typedef __attribute__((ext_vector_type(8))) short bf8_t;   // 8 x bf16
typedef __attribute__((ext_vector_type(4))) float f4_t;    // MFMA acc / float4
typedef __attribute__((ext_vector_type(4))) short s4_t;    // 4 x bf16 (8 B)

__device__ __forceinline__ short f2bf(float f) {
  unsigned u = __float_as_uint(f);
  u += 0x7fff + ((u >> 16) & 1);   // round-to-nearest-even
  return (short)(u >> 16);
}

// ======================= CSR build =======================
__global__ void count_deg_kernel(const int* __restrict__ dst, int* __restrict__ deg, int e_cnt) {
  int e = blockIdx.x * blockDim.x + threadIdx.x;
  if (e < e_cnt) atomicAdd(&deg[dst[e]], 1);
}

__global__ void scan_kernel(const int* __restrict__ deg, int* __restrict__ rowptr,
                            int* __restrict__ cursor, int n) {
  __shared__ int sdata[1024];
  __shared__ int s_carry;
  int tid = threadIdx.x;
  if (tid == 0) s_carry = 0;
  __syncthreads();
  for (int base = 0; base < n; base += 1024) {
    int idx = base + tid;
    int v = (idx < n) ? deg[idx] : 0;
    sdata[tid] = v;
    __syncthreads();
    for (int off = 1; off < 1024; off <<= 1) {
      int t = (tid >= off) ? sdata[tid - off] : 0;
      __syncthreads();
      sdata[tid] += t;
      __syncthreads();
    }
    int excl = sdata[tid] - v;
    if (idx < n) { int val = s_carry + excl; rowptr[idx] = val; cursor[idx] = val; }
    __syncthreads();
    if (tid == 0) s_carry += sdata[1023];
    __syncthreads();
  }
  if (tid == 0) rowptr[n] = s_carry;
}

__global__ void fill_csr_kernel(const int* __restrict__ src, const int* __restrict__ dst,
                                int* __restrict__ cursor, int* __restrict__ csr_src,
                                int* __restrict__ csr_eid, int e_cnt) {
  int e = blockIdx.x * blockDim.x + threadIdx.x;
  if (e < e_cnt) {
    int pos = atomicAdd(&cursor[dst[e]], 1);
    csr_src[pos] = src[e];
    csr_eid[pos] = e;
  }
}

// ======================= weight prep: fp32 -> bf16 transposed =======================
__global__ void prep_weights_kernel(const float* __restrict__ w1, const float* __restrict__ w2,
                                    short* __restrict__ w1t, short* __restrict__ w2t) {
  int i = blockIdx.x * blockDim.x + threadIdx.x;
  if (i < 16384) {
    int n = i >> 6, k = i & 63;
    w1t[n * 64 + k] = f2bf(w1[k * 256 + n]);
  } else if (i < 32768) {
    int j = i - 16384;
    int n = j >> 8, k = j & 255;
    w2t[n * 256 + k] = f2bf(w2[k * 64 + n]);
  }
}

// ======================= fp32 GEMM bodies =======================
template<int KIN>
__device__ __forceinline__ void gemm_body(
    const float* __restrict__ A, const float* __restrict__ W, int wld, int cb,
    int block_m, int M, float (&acc)[8][4],
    float (*As)[128 + 4], float (*Ws)[64 + 4])
{
  int tid = threadIdx.x;
  int tx = tid & 15;
  int ty = tid >> 4;
  #pragma unroll
  for (int i = 0; i < 8; ++i)
    #pragma unroll
    for (int j = 0; j < 4; ++j) acc[i][j] = 0.f;

  for (int k0 = 0; k0 < KIN; k0 += 16) {
    #pragma unroll
    for (int rep = 0; rep < 2; ++rep) {
      int ar = (tid >> 2) + rep * 64;
      int ak = (tid & 3) * 4;
      int gr = block_m + ar;
      float4 v = make_float4(0.f, 0.f, 0.f, 0.f);
      if (gr < M) v = *(const float4*)&A[(size_t)gr * KIN + k0 + ak];
      As[ak + 0][ar] = v.x; As[ak + 1][ar] = v.y;
      As[ak + 2][ar] = v.z; As[ak + 3][ar] = v.w;
    }
    {
      int wr = tid >> 4;
      int wc = (tid & 15) * 4;
      float4 v = *(const float4*)&W[(size_t)(k0 + wr) * wld + cb + wc];
      Ws[wr][wc + 0] = v.x; Ws[wr][wc + 1] = v.y;
      Ws[wr][wc + 2] = v.z; Ws[wr][wc + 3] = v.w;
    }
    __syncthreads();
    #pragma unroll
    for (int k = 0; k < 16; ++k) {
      float a[8], w[4];
      #pragma unroll
      for (int i = 0; i < 8; ++i) a[i] = As[k][ty * 8 + i];
      #pragma unroll
      for (int j = 0; j < 4; ++j) w[j] = Ws[k][tx * 4 + j];
      #pragma unroll
      for (int i = 0; i < 8; ++i)
        #pragma unroll
        for (int j = 0; j < 4; ++j) acc[i][j] = fmaf(a[i], w[j], acc[i][j]);
    }
    __syncthreads();
  }
}

// MODE 0: raw.  MODE 3: relu(v + bias).
template<int KIN, int MODE>
__global__ __launch_bounds__(256) void gemm64_kernel(
    const float* __restrict__ A, const float* __restrict__ W, int wld,
    const float* __restrict__ bias, float* __restrict__ out, int old, int M)
{
  __shared__ float As[16][128 + 4];
  __shared__ float Ws[16][64 + 4];
  float acc[8][4];
  int block_m = (int)blockIdx.x * 128;
  int cb = (int)blockIdx.y * 64;
  gemm_body<KIN>(A, W, wld, cb, block_m, M, acc, As, Ws);

  int tid = threadIdx.x;
  int tx = tid & 15, ty = tid >> 4;
  int gc = cb + tx * 4;
  #pragma unroll
  for (int i = 0; i < 8; ++i) {
    int gr = block_m + ty * 8 + i;
    if (gr >= M) continue;
    size_t idx = (size_t)gr * old + gc;
    float t0 = acc[i][0], t1 = acc[i][1], t2 = acc[i][2], t3 = acc[i][3];
    if (MODE == 3) {
      t0 = fmaxf(t0 + bias[gc + 0], 0.f);
      t1 = fmaxf(t1 + bias[gc + 1], 0.f);
      t2 = fmaxf(t2 + bias[gc + 2], 0.f);
      t3 = fmaxf(t3 + bias[gc + 3], 0.f);
    }
    *(float4*)&out[idx] = make_float4(t0, t1, t2, t3);
  }
}

// Pair GEMM for 256-wide projections: y<4 -> A@Wl colblock y -> xl; y>=4 -> A@Wr -> xr.
template<int KIN>
__global__ __launch_bounds__(256) void gemm_pair256_kernel(
    const float* __restrict__ A,
    const float* __restrict__ Wl, const float* __restrict__ Wr,
    float* __restrict__ xl, float* __restrict__ xr, int M)
{
  __shared__ float As[16][128 + 4];
  __shared__ float Ws[16][64 + 4];
  float acc[8][4];
  int block_m = (int)blockIdx.x * 128;
  int y = (int)blockIdx.y;
  const float* W = (y < 4) ? Wl : Wr;
  float* out = (y < 4) ? xl : xr;
  int cb = (y & 3) * 64;
  gemm_body<KIN>(A, W, 256, cb, block_m, M, acc, As, Ws);

  int tid = threadIdx.x;
  int tx = tid & 15, ty = tid >> 4;
  int gc = cb + tx * 4;
  #pragma unroll
  for (int i = 0; i < 8; ++i) {
    int gr = block_m + ty * 8 + i;
    if (gr >= M) continue;
    *(float4*)&out[(size_t)gr * 256 + gc] =
        make_float4(acc[i][0], acc[i][1], acc[i][2], acc[i][3]);
  }
}

// Dual 64-col GEMM: y==0 -> A@W0 -> out0 ; ==1 -> A@W1 -> out1.
template<int KIN>
__global__ __launch_bounds__(256) void gemm64_dual_kernel(
    const float* __restrict__ A,
    const float* __restrict__ W0, const float* __restrict__ W1, int wld,
    float* __restrict__ out0, float* __restrict__ out1, int M)
{
  __shared__ float As[16][128 + 4];
  __shared__ float Ws[16][64 + 4];
  float acc[8][4];
  int block_m = (int)blockIdx.x * 128;
  const float* W = (blockIdx.y == 0) ? W0 : W1;
  float* out = (blockIdx.y == 0) ? out0 : out1;
  gemm_body<KIN>(A, W, wld, 0, block_m, M, acc, As, Ws);

  int tid = threadIdx.x;
  int tx = tid & 15, ty = tid >> 4;
  int gc = tx * 4;
  #pragma unroll
  for (int i = 0; i < 8; ++i) {
    int gr = block_m + ty * 8 + i;
    if (gr >= M) continue;
    *(float4*)&out[(size_t)gr * 64 + gc] =
        make_float4(acc[i][0], acc[i][1], acc[i][2], acc[i][3]);
  }
}

// ======================= GATv2 aggregation =======================
#define AGG_UPD(P, X)                                     \
  {                                                       \
    float mn = fmaxf(m, (P));                             \
    float sc = __expf(m - mn);                            \
    float w  = __expf((P) - mn);                          \
    z = z * sc + w;                                       \
    acc = acc * sc + w * (X);                             \
    m = mn;                                               \
  }

#define AGG_BODY(STR)                                                         \
  float m, z, acc;                                                            \
  {                                                                           \
    float xs = xl[(size_t)d * STR + tid];                                     \
    float t = xs + xr_v;                                                      \
    t = t > 0.f ? t : 0.2f * t;                                               \
    float p = t * att_v;                                                      \
    _Pragma("unroll")                                                         \
    for (int off = 32; off > 0; off >>= 1) p += __shfl_xor(p, off, 64);       \
    m = p; z = 1.f; acc = xs;                                                 \
  }                                                                           \
  int j = 0;                                                                  \
  for (; j + 8 <= deg; j += 8) {                                              \
    int s[8]; float xv[8], p[8];                                              \
    _Pragma("unroll")                                                         \
    for (int u = 0; u < 8; ++u) s[u] = csr_src[row0 + j + u];                 \
    _Pragma("unroll")                                                         \
    for (int u = 0; u < 8; ++u) xv[u] = xl[(size_t)s[u] * STR + tid];         \
    _Pragma("unroll")                                                         \
    for (int u = 0; u < 8; ++u) {                                             \
      float t = xv[u] + xr_v;                                                 \
      t = t > 0.f ? t : 0.2f * t;                                             \
      p[u] = t * att_v;                                                       \
    }                                                                         \
    _Pragma("unroll")                                                         \
    for (int off = 32; off > 0; off >>= 1) {                                  \
      _Pragma("unroll")                                                       \
      for (int u = 0; u < 8; ++u) p[u] += __shfl_xor(p[u], off, 64);          \
    }                                                                         \
    _Pragma("unroll")                                                         \
    for (int u = 0; u < 8; ++u) AGG_UPD(p[u], xv[u]);                         \
  }                                                                           \
  for (; j + 4 <= deg; j += 4) {                                              \
    int s[4]; float xv[4], p[4];                                              \
    _Pragma("unroll")                                                         \
    for (int u = 0; u < 4; ++u) s[u] = csr_src[row0 + j + u];                 \
    _Pragma("unroll")                                                         \
    for (int u = 0; u < 4; ++u) xv[u] = xl[(size_t)s[u] * STR + tid];         \
    _Pragma("unroll")                                                         \
    for (int u = 0; u < 4; ++u) {                                             \
      float t = xv[u] + xr_v;                                                 \
      t = t > 0.f ? t : 0.2f * t;                                             \
      p[u] = t * att_v;                                                       \
    }                                                                         \
    _Pragma("unroll")                                                         \
    for (int off = 32; off > 0; off >>= 1) {                                  \
      _Pragma("unroll")                                                       \
      for (int u = 0; u < 4; ++u) p[u] += __shfl_xor(p[u], off, 64);          \
    }                                                                         \
    _Pragma("unroll")                                                         \
    for (int u = 0; u < 4; ++u) AGG_UPD(p[u], xv[u]);                         \
  }                                                                           \
  for (; j < deg; ++j) {                                                      \
    int s = csr_src[row0 + j];                                                \
    float x = xl[(size_t)s * STR + tid];                                      \
    float t = x + xr_v;                                                       \
    t = t > 0.f ? t : 0.2f * t;                                               \
    float p = t * att_v;                                                      \
    _Pragma("unroll")                                                         \
    for (int off = 32; off > 0; off >>= 1) p += __shfl_xor(p, off, 64);       \
    AGG_UPD(p, x);                                                            \
  }

// single-head, one wave per destination, stride 64
template<bool ELU>
__global__ __launch_bounds__(64) void gat_agg64(
    const float* __restrict__ xl, const float* __restrict__ xr,
    const float* __restrict__ att, const float* __restrict__ bias,
    const int* __restrict__ rowptr, const int* __restrict__ csr_src,
    float* __restrict__ out, int old)
{
  int d = blockIdx.x;
  int tid = threadIdx.x;
  int row0 = rowptr[d];
  int deg = rowptr[d + 1] - row0;
  float xr_v = xr[(size_t)d * 64 + tid];
  float att_v = att[tid];
  AGG_BODY(64)
  float val = acc / z + bias[tid];
  if (ELU) val = val > 0.f ? val : __expf(val) - 1.f;
  out[(size_t)d * old + tid] = val;
}

// 4-head fused: block=256 (wave h = head h), xl/xr/out stride 256, concat layout.
template<bool ELU>
__global__ __launch_bounds__(256) void gat_agg256(
    const float* __restrict__ xl, const float* __restrict__ xr,
    const float* __restrict__ att, const float* __restrict__ bias,
    const int* __restrict__ rowptr, const int* __restrict__ csr_src,
    float* __restrict__ out)
{
  int d = blockIdx.x;
  int tid = threadIdx.x;
  int row0 = rowptr[d];
  int deg = rowptr[d + 1] - row0;
  float xr_v = xr[(size_t)d * 256 + tid];
  float att_v = att[tid];
  AGG_BODY(256)
  float val = acc / z + bias[tid];
  if (ELU) val = val > 0.f ? val : __expf(val) - 1.f;
  out[(size_t)d * 256 + tid] = val;
}

// ======================= fused MFMA chunk kernel (edge rows >= N) =======================
// Register-lean: GEMM1 one nt at a time (8 live acc regs), wave-private LDS,
// no barriers, per-edge p-pair written coalesced to pbuf (NO atomics).
__global__ __launch_bounds__(256, 4) void chunk_fused_kernel(
    const float* __restrict__ A,      // edge_type + N*64
    const short* __restrict__ W1t,    // [256][64] bf16 (n,k)  == W1^T
    const short* __restrict__ W2t,    // [64][256] bf16 (n,k)  == W2^T
    const float* __restrict__ b1,     // [256]
    const float* __restrict__ b2,     // [64]
    const float* __restrict__ wp,     // [64][2]
    float* __restrict__ pbufN,        // pbuf + 2*N_NODES (indexed by local row)
    int Mtot)
{
  __shared__ short gbuf[4][32][72];   // per-wave [row][col], pad 64->72
  int tid = threadIdx.x;
  int w = tid >> 6;
  int lane = tid & 63;
  int quad = lane >> 4;
  int l15 = lane & 15;
  int row_base = (int)blockIdx.x * 128 + w * 32;

  // row frags: lane l15 = row, k = ks*32 + quad*8 + j
  bf8_t a1[2][2];
  #pragma unroll
  for (int rt = 0; rt < 2; ++rt) {
    int r = row_base + rt * 16 + l15;
    int rc = r < Mtot ? r : Mtot - 1;
    const float* ap = A + (size_t)rc * 64 + quad * 8;
    #pragma unroll
    for (int ks = 0; ks < 2; ++ks) {
      float4 v0 = *(const float4*)(ap + ks * 32);
      float4 v1 = *(const float4*)(ap + ks * 32 + 4);
      bf8_t f;
      f[0] = f2bf(v0.x); f[1] = f2bf(v0.y); f[2] = f2bf(v0.z); f[3] = f2bf(v0.w);
      f[4] = f2bf(v1.x); f[5] = f2bf(v1.y); f[6] = f2bf(v1.z); f[7] = f2bf(v1.w);
      a1[rt][ks] = f;
    }
  }

  f4_t accr[2][4];
  #pragma unroll
  for (int rt = 0; rt < 2; ++rt)
    #pragma unroll
    for (int nt = 0; nt < 4; ++nt) {
      f4_t zz = {0.f, 0.f, 0.f, 0.f};
      accr[rt][nt] = zz;
    }

  for (int cc = 0; cc < 4; ++cc) {
    // ---- GEMM1 transposed, one nt tile at a time (low register pressure) ----
    #pragma unroll
    for (int nt = 0; nt < 4; ++nt) {
      const short* wb = W1t + (cc * 64 + nt * 16 + l15) * 64 + quad * 8;
      bf8_t w0 = *(const bf8_t*)(wb);
      bf8_t w1 = *(const bf8_t*)(wb + 32);
      f4_t g0 = {0.f, 0.f, 0.f, 0.f};
      f4_t g1 = {0.f, 0.f, 0.f, 0.f};
      g0 = __builtin_amdgcn_mfma_f32_16x16x32_bf16(w0, a1[0][0], g0, 0, 0, 0);
      g0 = __builtin_amdgcn_mfma_f32_16x16x32_bf16(w1, a1[0][1], g0, 0, 0, 0);
      g1 = __builtin_amdgcn_mfma_f32_16x16x32_bf16(w0, a1[1][0], g1, 0, 0, 0);
      g1 = __builtin_amdgcn_mfma_f32_16x16x32_bf16(w1, a1[1][1], g1, 0, 0, 0);
      // lane reg r = G[row = l15 (+16*rt)][col = cc*64 + nt*16 + quad*4 + r]
      f4_t b4 = *(const f4_t*)&b1[cc * 64 + nt * 16 + quad * 4];
      s4_t pk0, pk1;
      #pragma unroll
      for (int r = 0; r < 4; ++r) {
        float v = g0[r] + b4[r];
        v = v > 0.f ? v : __expf(v) - 1.f;
        pk0[r] = f2bf(v);
        float u = g1[r] + b4[r];
        u = u > 0.f ? u : __expf(u) - 1.f;
        pk1[r] = f2bf(u);
      }
      *(s4_t*)&gbuf[w][l15][nt * 16 + quad * 4] = pk0;
      *(s4_t*)&gbuf[w][16 + l15][nt * 16 + quad * 4] = pk1;
    }
    // ---- read back as A-frags (in-order DS within wave: no barrier) ----
    bf8_t a2[2][2];
    #pragma unroll
    for (int rt = 0; rt < 2; ++rt)
      #pragma unroll
      for (int ks = 0; ks < 2; ++ks)
        a2[rt][ks] = *(const bf8_t*)&gbuf[w][rt * 16 + l15][ks * 32 + quad * 8];
    // ---- GEMM2 accumulate over this K-chunk ----
    #pragma unroll
    for (int nt = 0; nt < 4; ++nt) {
      const short* wb = W2t + (nt * 16 + l15) * 256 + cc * 64 + quad * 8;
      bf8_t bk0 = *(const bf8_t*)(wb);
      bf8_t bk1 = *(const bf8_t*)(wb + 32);
      #pragma unroll
      for (int rt = 0; rt < 2; ++rt) {
        accr[rt][nt] = __builtin_amdgcn_mfma_f32_16x16x32_bf16(a2[rt][0], bk0, accr[rt][nt], 0, 0, 0);
        accr[rt][nt] = __builtin_amdgcn_mfma_f32_16x16x32_bf16(a2[rt][1], bk1, accr[rt][nt], 0, 0, 0);
      }
    }
  }

  // ---- R epilogue: +b2, dot with wp, reduce over l15, write pbuf ----
  #pragma unroll
  for (int rt = 0; rt < 2; ++rt) {
    float p0[4] = {0.f, 0.f, 0.f, 0.f};
    float p1[4] = {0.f, 0.f, 0.f, 0.f};
    #pragma unroll
    for (int nt = 0; nt < 4; ++nt) {
      int col = nt * 16 + l15;
      float bias = b2[col];
      float w0 = wp[col * 2 + 0], w1 = wp[col * 2 + 1];
      #pragma unroll
      for (int r = 0; r < 4; ++r) {
        float v = accr[rt][nt][r] + bias;
        p0[r] = fmaf(v, w0, p0[r]);
        p1[r] = fmaf(v, w1, p1[r]);
      }
    }
    #pragma unroll
    for (int r = 0; r < 4; ++r) {
      #pragma unroll
      for (int off = 1; off < 16; off <<= 1) {
        p0[r] += __shfl_xor(p0[r], off, 64);
        p1[r] += __shfl_xor(p1[r], off, 64);
      }
    }
    if (l15 == 0) {
      #pragma unroll
      for (int r = 0; r < 4; ++r) {
        int row = row_base + rt * 16 + quad * 4 + r;
        if (row < Mtot) {
          float2 pv = make_float2(p0[r], p1[r]);
          *(float2*)&pbufN[2 * row] = pv;
        }
      }
    }
  }
}

// ======================= per-edge p for edge ids < N (no atomics) =======================
__global__ void edge_dot_kernel(const float* __restrict__ edge_repr, const float* __restrict__ wp,
                                float* __restrict__ pbuf, int e_cnt) {
  __shared__ float swp[128];
  if (threadIdx.x < 128) swp[threadIdx.x] = wp[threadIdx.x];
  __syncthreads();
  int e = blockIdx.x * blockDim.x + threadIdx.x;
  if (e >= e_cnt) return;
  const float* er = edge_repr + (size_t)e * 64;
  float a0 = 0.f, a1 = 0.f;
  #pragma unroll
  for (int k = 0; k < 64; ++k) {
    float v = er[k];
    a0 = fmaf(v, swp[2 * k + 0], a0);
    a1 = fmaf(v, swp[2 * k + 1], a1);
  }
  *(float2*)&pbuf[2 * e] = make_float2(a0, a1);
}

// ======================= Heads: CSR-gather msg + log_softmax + proxy =======================
__global__ void head_kernel(const float* __restrict__ node_repr, const float* __restrict__ ph,
                            const int* __restrict__ rowptr, const int* __restrict__ csr_eid,
                            const float* __restrict__ pbuf, const float* __restrict__ wu,
                            const float* __restrict__ bu, const float* __restrict__ w2,
                            const float* __restrict__ b2, float* __restrict__ out, int n) {
  __shared__ float swu[128];
  __shared__ float sw2[256];
  int tid = threadIdx.x;
  if (tid < 128) swu[tid] = wu[tid];
  sw2[tid] = w2[tid];
  __syncthreads();
  int i = blockIdx.x * blockDim.x + tid;
  if (i >= n) return;
  // msg gather over in-edges
  float m0 = 0.f, m1 = 0.f;
  int r0 = rowptr[i], r1 = rowptr[i + 1];
  int jj = r0;
  for (; jj + 4 <= r1; jj += 4) {
    int e0 = csr_eid[jj + 0], e1 = csr_eid[jj + 1];
    int e2 = csr_eid[jj + 2], e3 = csr_eid[jj + 3];
    float2 q0 = *(const float2*)&pbuf[2 * e0];
    float2 q1 = *(const float2*)&pbuf[2 * e1];
    float2 q2 = *(const float2*)&pbuf[2 * e2];
    float2 q3 = *(const float2*)&pbuf[2 * e3];
    m0 += (q0.x + q1.x) + (q2.x + q3.x);
    m1 += (q0.y + q1.y) + (q2.y + q3.y);
  }
  for (; jj < r1; ++jj) {
    int e = csr_eid[jj];
    float2 q = *(const float2*)&pbuf[2 * e];
    m0 += q.x; m1 += q.y;
  }
  const float* nr = node_repr + (size_t)i * 64;
  float u0 = bu[0], u1 = bu[1];
  #pragma unroll
  for (int k = 0; k < 64; ++k) {
    float v = nr[k];
    u0 = fmaf(v, swu[2 * k + 0], u0);
    u1 = fmaf(v, swu[2 * k + 1], u1);
  }
  float v0 = u0 + m0;
  float v1 = u1 + m1;
  float mx = fmaxf(v0, v1);
  float lse = mx + logf(__expf(v0 - mx) + __expf(v1 - mx));
  out[2 * i + 0] = v0 - lse;
  out[2 * i + 1] = v1 - lse;
  const float* p = ph + (size_t)i * 128;
  float p0 = b2[0], p1 = b2[1];
  #pragma unroll
  for (int k = 0; k < 128; ++k) {
    float v = p[k];
    p0 = fmaf(v, sw2[2 * k + 0], p0);
    p1 = fmaf(v, sw2[2 * k + 1], p1);
  }
  out[2 * n + 2 * i + 0] = p0;
  out[2 * n + 2 * i + 1] = p1;
}

// ======================= launch =======================
extern "C" void kernel_launch(void* const* d_in, const int* in_sizes, int n_in,
                              void* d_out, int out_size, void* d_ws, size_t ws_size,
                              hipStream_t stream) {
  const int N = N_NODES, E = N_EDGES;
  const float* x         = (const float*)d_in[0];
  const float* edge_type = (const float*)d_in[1];
  const int*   ei        = (const int*)d_in[2];
  const float* n1_wl  = (const float*)d_in[3];
  const float* n1_wr  = (const float*)d_in[4];
  const float* n1_att = (const float*)d_in[5];
  const float* n1_b   = (const float*)d_in[6];
  const float* n2_wl  = (const float*)d_in[7];
  const float* n2_wr  = (const float*)d_in[8];
  const float* n2_att = (const float*)d_in[9];
  const float* n2_b   = (const float*)d_in[10];
  const float* e1_wl  = (const float*)d_in[11];
  const float* e1_wr  = (const float*)d_in[12];
  const float* e1_att = (const float*)d_in[13];
  const float* e1_b   = (const float*)d_in[14];
  const float* e2_wl  = (const float*)d_in[15];
  const float* e2_wr  = (const float*)d_in[16];
  const float* e2_att = (const float*)d_in[17];
  const float* e2_b   = (const float*)d_in[18];
  const float* crf_wu = (const float*)d_in[19];
  const float* crf_bu = (const float*)d_in[20];
  const float* crf_wp = (const float*)d_in[21];
  const float* px_w1  = (const float*)d_in[22];
  const float* px_b1  = (const float*)d_in[23];
  const float* px_w2  = (const float*)d_in[24];
  const float* px_b2  = (const float*)d_in[25];
  float* out = (float*)d_out;
  const int* src = ei;
  const int* dst = ei + E;
  (void)in_sizes; (void)n_in; (void)out_size; (void)ws_size;

  // ---- workspace layout (~80 MB of ~327 MB) ----
  char* ws = (char*)d_ws;
  size_t off = 0;
  auto alloc = [&](size_t bytes) -> void* {
    void* p = ws + off;
    off += (bytes + 255) & ~(size_t)255;
    return p;
  };
  float* arena0 = (float*)alloc((size_t)N * 256 * 4);  // xl / [N,64] views / ph
  float* arena1 = (float*)alloc((size_t)N * 256 * 4);  // xr
  float* arena2 = (float*)alloc((size_t)N * 256 * 4);  // h / g_low
  float* ph     = arena0;
  float* B3    = (float*)alloc((size_t)N * 64 * 4);    // node_repr
  float* erlow = (float*)alloc((size_t)N * 64 * 4);    // edge_repr rows < N
  float* pbuf  = (float*)alloc((size_t)E * 2 * 4);     // per-edge CRF p-pairs
  int* deg     = (int*)alloc((size_t)N * 4);
  int* rowptr  = (int*)alloc((size_t)(N + 1) * 4);
  int* cursor  = (int*)alloc((size_t)N * 4);
  int* csr_src = (int*)alloc((size_t)E * 4);
  int* csr_eid = (int*)alloc((size_t)E * 4);
  short* W1t   = (short*)alloc((size_t)256 * 64 * 2);
  short* W2t   = (short*)alloc((size_t)64 * 256 * 2);

  const int EB = (E + 255) / 256;
  const int NB = (N + 127) / 128;        // 157
  const int Mhigh = E - N;               // 300000
  const int CFB = (Mhigh + 127) / 128;   // 2344

  hipMemsetAsync(deg, 0, (size_t)N * 4, stream);
  count_deg_kernel<<<EB, 256, 0, stream>>>(dst, deg, E);
  scan_kernel<<<1, 1024, 0, stream>>>(deg, rowptr, cursor, N);
  fill_csr_kernel<<<EB, 256, 0, stream>>>(src, dst, cursor, csr_src, csr_eid, E);
  prep_weights_kernel<<<128, 256, 0, stream>>>(e1_wl, e2_wl, W1t, W2t);

  // ---- node layer 1: GATv2(64 -> 4x64, concat) + elu ----
  gemm_pair256_kernel<64><<<dim3(NB, 8), 256, 0, stream>>>(x, n1_wl, n1_wr, arena0, arena1, N);
  gat_agg256<true><<<N, 256, 0, stream>>>(arena0, arena1, n1_att, n1_b, rowptr, csr_src, arena2);

  // ---- node layer 2: GATv2(256 -> 64) -> B3 ----
  gemm64_dual_kernel<256><<<dim3(NB, 2), 256, 0, stream>>>(arena2, n2_wl, n2_wr, 64, arena0, arena1, N);
  gat_agg64<false><<<N, 64, 0, stream>>>(arena0, arena1, n2_att, n2_b, rowptr, csr_src, B3, 64);

  // ---- edge layer 1, rows < N ----
  gemm_pair256_kernel<64><<<dim3(NB, 8), 256, 0, stream>>>(edge_type, e1_wl, e1_wr, arena0, arena1, N);
  gat_agg256<true><<<N, 256, 0, stream>>>(arena0, arena1, e1_att, e1_b, rowptr, csr_src, arena2);

  // ---- edge layer 2, rows < N -> erlow ----
  gemm64_dual_kernel<256><<<dim3(NB, 2), 256, 0, stream>>>(arena2, e2_wl, e2_wr, 64, arena0, arena1, N);
  gat_agg64<false><<<N, 64, 0, stream>>>(arena0, arena1, e2_att, e2_b, rowptr, csr_src, erlow, 64);

  // ---- CRF per-edge p pairs (no atomics) ----
  edge_dot_kernel<<<(N + 255) / 256, 256, 0, stream>>>(erlow, crf_wp, pbuf, N);
  chunk_fused_kernel<<<CFB, 256, 0, stream>>>(edge_type + (size_t)N * 64, W1t, W2t,
                                              e1_b, e2_b, crf_wp, pbuf + 2 * (size_t)N, Mhigh);

  // ---- heads ----
  gemm64_kernel<64, 3><<<dim3(NB, 2), 256, 0, stream>>>(B3, px_w1, 128, px_b1, ph, 128, N);
  head_kernel<<<(N + 255) / 256, 256, 0, stream>>>(B3, ph, rowptr, csr_eid, pbuf,
                                                   crf_wu, crf_bu, px_w2, px_b2, out, N);
}